// Round 1
// baseline (65.422 us; speedup 1.0000x reference)
//
#include <hip/hip_runtime.h>

// ParticleI2cCell: pairwise Gaussian loglik (P x P, D=4) + two row-LSEs.
// smoothed[i] = log(sum_j e_ij * exp(w_j)) - log(sum_j e_ij * exp(lw_j)),
// e_ij = exp(-0.5*||m_i - s_j||^2)  (fixed max = 0; constants cancel).

constexpr int DXc = 4;
constexpr int DUc = 2;
constexpr float LOG2E = 1.4426950408889634f;
constexpr float LN2   = 0.6931471805599453f;

// ---------------- precompute: per-j table [P][8] and per-i {m4, c2} ---------
__global__ void precompute_kernel(const float* __restrict__ particles,
                                  const float* __restrict__ samples,
                                  const float* __restrict__ weights,
                                  const float* __restrict__ log_weights,
                                  const float* __restrict__ A,
                                  const float* __restrict__ B,
                                  const float* __restrict__ log_sigma,
                                  float* __restrict__ jdata,  // [P][8]
                                  float* __restrict__ m4,     // [P][4]
                                  float* __restrict__ c2,     // [P]
                                  int P)
{
    int i = blockIdx.x * blockDim.x + threadIdx.x;
    if (i >= P) return;

    const float K = -0.5f * LOG2E;   // so t = K*sq and e = exp2(t) = exp(-sq/2)

    float inv_s[DXc];
#pragma unroll
    for (int k = 0; k < DXc; ++k)
        inv_s[k] = __builtin_amdgcn_exp2f(-log_sigma[k] * LOG2E);

    // ---- j side: scaled sample, squared norm, exp(weights) ----
    float s[DXc];
    float s2 = 0.f;
#pragma unroll
    for (int k = 0; k < DXc; ++k) {
        s[k] = samples[i * DXc + k] * inv_s[k];
        s2 = fmaf(s[k], s[k], s2);
    }
    float* jd = jdata + (size_t)i * 8;
    jd[0] = -2.f * K * s[0];
    jd[1] = -2.f * K * s[1];
    jd[2] = -2.f * K * s[2];
    jd[3] = -2.f * K * s[3];
    jd[4] = K * s2;
    jd[5] = __builtin_amdgcn_exp2f(log_weights[i] * LOG2E);  // exp(lw)
    jd[6] = __builtin_amdgcn_exp2f(weights[i] * LOG2E);      // exp(w)
    jd[7] = 0.f;

    // ---- i side: mean = x A^T + u B^T, scaled ----
    float x[DXc], u[DUc];
#pragma unroll
    for (int k = 0; k < DXc; ++k) x[k] = particles[i * (DXc + DUc) + k];
#pragma unroll
    for (int k = 0; k < DUc; ++k) u[k] = particles[i * (DXc + DUc) + DXc + k];

    float m2 = 0.f;
    float mk[DXc];
#pragma unroll
    for (int k = 0; k < DXc; ++k) {
        float mean = 0.f;
#pragma unroll
        for (int kk = 0; kk < DXc; ++kk) mean = fmaf(A[k * DXc + kk], x[kk], mean);
#pragma unroll
        for (int kk = 0; kk < DUc; ++kk) mean = fmaf(B[k * DUc + kk], u[kk], mean);
        mk[k] = mean * inv_s[k];
        m2 = fmaf(mk[k], mk[k], m2);
    }
    float4 mv = make_float4(mk[0], mk[1], mk[2], mk[3]);
    *reinterpret_cast<float4*>(m4 + (size_t)i * 4) = mv;
    c2[i] = K * m2;
}

// ---------------- main pairwise kernel: R rows/thread, j-chunk per block ----
template <int R, int BLOCK>
__global__ __launch_bounds__(BLOCK) void pair_kernel(
    const float* __restrict__ jdata,  // [P][8]
    const float* __restrict__ m4,     // [P][4]
    const float* __restrict__ c2,     // [P]
    float* __restrict__ part1,        // [NJ][P]
    float* __restrict__ part2,        // [NJ][P]
    int P, int jchunk)
{
    const int tid = threadIdx.x;
    const int jc = blockIdx.x;
    const int rowBase = blockIdx.y * (BLOCK * R);
    const int j0 = jc * jchunk;

    float m0[R], m1[R], m2r[R], m3[R], cc[R], s1[R], s2[R];
#pragma unroll
    for (int r = 0; r < R; ++r) {
        int row = rowBase + tid + r * BLOCK;
        float4 mv = *reinterpret_cast<const float4*>(m4 + (size_t)row * 4);
        m0[r] = mv.x; m1[r] = mv.y; m2r[r] = mv.z; m3[r] = mv.w;
        cc[r] = c2[row];
        s1[r] = 0.f;
        s2[r] = 0.f;
    }

    const float* jd = jdata + (size_t)j0 * 8;
#pragma unroll 2
    for (int jj = 0; jj < jchunk; ++jj, jd += 8) {
        // wave-uniform address -> broadcast / scalar loads
        float a0 = jd[0], a1 = jd[1], a2 = jd[2], a3 = jd[3];
        float cj = jd[4], elw = jd[5], ew = jd[6];
#pragma unroll
        for (int r = 0; r < R; ++r) {
            float t = cc[r] + cj;
            t = fmaf(m0[r], a0, t);
            t = fmaf(m1[r], a1, t);
            t = fmaf(m2r[r], a2, t);
            t = fmaf(m3[r], a3, t);
            float e = __builtin_amdgcn_exp2f(t);   // exp(-0.5*sq)
            s1[r] = fmaf(e, elw, s1[r]);
            s2[r] = fmaf(e, ew, s2[r]);
        }
    }

#pragma unroll
    for (int r = 0; r < R; ++r) {
        int row = rowBase + tid + r * BLOCK;
        part1[(size_t)jc * P + row] = s1[r];
        part2[(size_t)jc * P + row] = s2[r];
    }
}

// ---------------- reduce: fixed-order sum over NJ partials, log-ratio ------
__global__ void reduce_kernel(const float* __restrict__ part1,
                              const float* __restrict__ part2,
                              float* __restrict__ out, int P, int NJ)
{
    int i = blockIdx.x * blockDim.x + threadIdx.x;
    if (i >= P) return;
    float s1 = 0.f, s2 = 0.f;
    for (int nj = 0; nj < NJ; ++nj) {
        s1 += part1[(size_t)nj * P + i];
        s2 += part2[(size_t)nj * P + i];
    }
    out[i] = (__builtin_amdgcn_logf(s2) - __builtin_amdgcn_logf(s1)) * LN2;
}

extern "C" void kernel_launch(void* const* d_in, const int* in_sizes, int n_in,
                              void* d_out, int out_size, void* d_ws, size_t ws_size,
                              hipStream_t stream)
{
    const float* particles   = (const float*)d_in[0];
    const float* samples     = (const float*)d_in[1];
    const float* weights     = (const float*)d_in[2];
    const float* log_weights = (const float*)d_in[3];
    const float* A           = (const float*)d_in[4];
    const float* B           = (const float*)d_in[5];
    const float* log_sigma   = (const float*)d_in[6];

    const int P = in_sizes[2];  // weights is (P,)

    float* ws    = (float*)d_ws;
    float* jdata = ws;                       // P*8
    float* m4    = jdata + (size_t)P * 8;    // P*4
    float* c2    = m4 + (size_t)P * 4;       // P
    float* part1 = c2 + (size_t)P;           // NJ*P
    // pick NJ (j-split) that fits the workspace; deterministic given ws_size
    size_t base_bytes = (size_t)P * 13 * sizeof(float);
    int NJ = 64;
    while (NJ > 1 && base_bytes + (size_t)2 * NJ * P * sizeof(float) > ws_size)
        NJ >>= 1;
    float* part2 = part1 + (size_t)NJ * P;

    precompute_kernel<<<(P + 255) / 256, 256, 0, stream>>>(
        particles, samples, weights, log_weights, A, B, log_sigma,
        jdata, m4, c2, P);

    constexpr int R = 8, BLOCK = 256;
    int rowBlocks = P / (R * BLOCK);         // 8192/2048 = 4
    dim3 grid(NJ, rowBlocks);
    pair_kernel<R, BLOCK><<<grid, BLOCK, 0, stream>>>(
        jdata, m4, c2, part1, part2, P, P / NJ);

    reduce_kernel<<<(P + 255) / 256, 256, 0, stream>>>(
        part1, part2, (float*)d_out, P, NJ);
}

// Round 2
// 32.327 us; speedup vs baseline: 2.0238x; 2.0238x over previous
//
#include <hip/hip_runtime.h>

// ParticleI2cCell: pairwise Gaussian loglik (P x P, D=4) + two row-LSEs.
// smoothed[i] = log(sum_j e_ij*exp(w_j)) - log(sum_j e_ij*exp(lw_j))
// e_ij = exp(m_i . s_j - ||s_j||^2/2)   [the exp(-||m_i||^2/2) factor is
// constant over j and cancels in the log-ratio, so it is dropped].

constexpr int DXc = 4;
constexpr int DUc = 2;
constexpr float LOG2E = 1.4426950408889634f;
constexpr float LN2   = 0.6931471805599453f;

// ---------------- fused pair kernel --------------------------------------
// grid = (NJ, P/(R*BLOCK)). Each block: stage JCHUNK j-entries in LDS
// (computed from raw inputs), compute R row-means per thread, then the
// JCHUNK x (R*BLOCK) pair tile, writing two partial sums per row.
template <int R, int BLOCK, int JCHUNK>
__global__ __launch_bounds__(BLOCK) void pair_fused(
    const float* __restrict__ particles,
    const float* __restrict__ samples,
    const float* __restrict__ weights,
    const float* __restrict__ log_weights,
    const float* __restrict__ A,
    const float* __restrict__ B,
    const float* __restrict__ log_sigma,
    float* __restrict__ part1,        // [NJ][P]
    float* __restrict__ part2,        // [NJ][P]
    int P)
{
    const int tid = threadIdx.x;
    const int jc  = blockIdx.x;
    const int rowBase = blockIdx.y * (BLOCK * R);

    __shared__ __align__(16) float jds[JCHUNK * 8];

    const float K = -0.5f * LOG2E;

    float inv_s[DXc];
#pragma unroll
    for (int k = 0; k < DXc; ++k)
        inv_s[k] = __builtin_amdgcn_exp2f(-log_sigma[k] * LOG2E);

    // ---- stage j-entries: a = LOG2E*s, b = {K*||s||^2, e^lw, e^w, 0} ----
    if (tid < JCHUNK) {
        int j = jc * JCHUNK + tid;
        float4 sv = reinterpret_cast<const float4*>(samples)[j];
        float s0 = sv.x * inv_s[0], s1 = sv.y * inv_s[1];
        float s2 = sv.z * inv_s[2], s3 = sv.w * inv_s[3];
        float sn = s0*s0 + s1*s1 + s2*s2 + s3*s3;
        float4 av = make_float4(LOG2E*s0, LOG2E*s1, LOG2E*s2, LOG2E*s3);
        float4 bv = make_float4(K * sn,
                                __builtin_amdgcn_exp2f(log_weights[j] * LOG2E),
                                __builtin_amdgcn_exp2f(weights[j] * LOG2E),
                                0.f);
        reinterpret_cast<float4*>(jds)[tid * 2]     = av;
        reinterpret_cast<float4*>(jds)[tid * 2 + 1] = bv;
    }

    // ---- per-thread row means (R rows, strided by BLOCK) ----
    float m0[R], m1[R], m2[R], m3[R], acc1[R], acc2[R];
#pragma unroll
    for (int r = 0; r < R; ++r) {
        int row = rowBase + tid + r * BLOCK;
        const float2* p2 = reinterpret_cast<const float2*>(particles) + (size_t)row * 3;
        float2 x01 = p2[0], x23 = p2[1], u01 = p2[2];
        float x[4] = {x01.x, x01.y, x23.x, x23.y};
        float u[2] = {u01.x, u01.y};
        float mk[4];
#pragma unroll
        for (int k = 0; k < 4; ++k) {
            float mean =       A[k*4+0] * x[0];
            mean = fmaf(A[k*4+1], x[1], mean);
            mean = fmaf(A[k*4+2], x[2], mean);
            mean = fmaf(A[k*4+3], x[3], mean);
            mean = fmaf(B[k*2+0], u[0], mean);
            mean = fmaf(B[k*2+1], u[1], mean);
            mk[k] = mean * inv_s[k];
        }
        m0[r] = mk[0]; m1[r] = mk[1]; m2[r] = mk[2]; m3[r] = mk[3];
        acc1[r] = 0.f; acc2[r] = 0.f;
    }

    __syncthreads();

    // ---- pair tile: 6 FMA + 1 exp2 per pair ----
    const float4* jf = reinterpret_cast<const float4*>(jds);
#pragma unroll 4
    for (int jj = 0; jj < JCHUNK; ++jj) {
        float4 av = jf[jj * 2];
        float4 bv = jf[jj * 2 + 1];
#pragma unroll
        for (int r = 0; r < R; ++r) {
            float t = fmaf(m0[r], av.x, bv.x);
            t = fmaf(m1[r], av.y, t);
            t = fmaf(m2[r], av.z, t);
            t = fmaf(m3[r], av.w, t);
            float e = __builtin_amdgcn_exp2f(t);
            acc1[r] = fmaf(e, bv.y, acc1[r]);
            acc2[r] = fmaf(e, bv.z, acc2[r]);
        }
    }

#pragma unroll
    for (int r = 0; r < R; ++r) {
        int row = rowBase + tid + r * BLOCK;
        part1[(size_t)jc * P + row] = acc1[r];
        part2[(size_t)jc * P + row] = acc2[r];
    }
}

// ---------------- reduce: 64 rows/block x 4 nj-slices, fixed order --------
__global__ __launch_bounds__(256) void reduce_kernel(
    const float* __restrict__ part1,
    const float* __restrict__ part2,
    float* __restrict__ out, int P, int NJ)
{
    const int rl = threadIdx.x & 63;
    const int sl = threadIdx.x >> 6;          // 0..3
    const int row = blockIdx.x * 64 + rl;

    float s1 = 0.f, s2 = 0.f;
    for (int nj = sl; nj < NJ; nj += 4) {
        s1 += part1[(size_t)nj * P + row];
        s2 += part2[(size_t)nj * P + row];
    }
    __shared__ float l1[4][64], l2[4][64];
    l1[sl][rl] = s1; l2[sl][rl] = s2;
    __syncthreads();
    if (sl == 0) {
        float t1 = ((l1[0][rl] + l1[1][rl]) + l1[2][rl]) + l1[3][rl];
        float t2 = ((l2[0][rl] + l2[1][rl]) + l2[2][rl]) + l2[3][rl];
        out[row] = (__builtin_amdgcn_logf(t2) - __builtin_amdgcn_logf(t1)) * LN2;
    }
}

extern "C" void kernel_launch(void* const* d_in, const int* in_sizes, int n_in,
                              void* d_out, int out_size, void* d_ws, size_t ws_size,
                              hipStream_t stream)
{
    const float* particles   = (const float*)d_in[0];
    const float* samples     = (const float*)d_in[1];
    const float* weights     = (const float*)d_in[2];
    const float* log_weights = (const float*)d_in[3];
    const float* A           = (const float*)d_in[4];
    const float* B           = (const float*)d_in[5];
    const float* log_sigma   = (const float*)d_in[6];

    const int P = in_sizes[2];  // weights is (P,)

    // pick NJ that fits workspace (2*NJ*P floats); deterministic
    int NJ = 128;
    while (NJ > 32 && (size_t)2 * NJ * P * sizeof(float) > ws_size)
        NJ >>= 1;

    float* part1 = (float*)d_ws;
    float* part2 = part1 + (size_t)NJ * P;

    constexpr int R = 4, BLOCK = 256;
    dim3 grid(NJ, P / (R * BLOCK));

    switch (NJ) {
    case 128:
        pair_fused<R, BLOCK, 64><<<grid, BLOCK, 0, stream>>>(
            particles, samples, weights, log_weights, A, B, log_sigma,
            part1, part2, P);
        break;
    case 64:
        pair_fused<R, BLOCK, 128><<<grid, BLOCK, 0, stream>>>(
            particles, samples, weights, log_weights, A, B, log_sigma,
            part1, part2, P);
        break;
    default:
        pair_fused<R, BLOCK, 256><<<grid, BLOCK, 0, stream>>>(
            particles, samples, weights, log_weights, A, B, log_sigma,
            part1, part2, P);
        break;
    }

    reduce_kernel<<<P / 64, 256, 0, stream>>>(part1, part2, (float*)d_out, P, NJ);
}